// Round 4
// baseline (471.676 us; speedup 1.0000x reference)
//
#include <hip/hip_runtime.h>
#include <stdint.h>

#define N_NODES 50000
#define N_EDGES 800000
#define IN_F 128
#define HEADS 8
#define HEAD_DIM 16
#define ALPHA 0.2f
#define EPSV 1e-6f

__device__ __forceinline__ void atomicMaxF(float* addr, float val) {
    int* ia = (int*)addr;
    int old = *ia;
    while (__int_as_float(old) < val) {
        int assumed = old;
        old = atomicCAS(ia, assumed, __float_as_int(val));
        if (old == assumed) break;
    }
}

// ---------------- init: zero deg, maxss/maxst = -inf
__global__ __launch_bounds__(256) void k_init(int* __restrict__ deg,
                                              float* __restrict__ maxss,
                                              float* __restrict__ maxst) {
    int i = blockIdx.x * 256 + threadIdx.x;
    if (i < N_NODES) deg[i] = 0;
    if (i < 8) { maxss[i] = -INFINITY; maxst[i] = -INFINITY; }
}

// ---------------- k1: h = x @ W  (+ fused s_src/s_tgt projections)
// one wave per node; lane owns cols c0=lane, c1=lane+64 (col = head*16+d)
__global__ __launch_bounds__(256) void k1_gemm(const float* __restrict__ x,
                                               const float* __restrict__ W,
                                               const float* __restrict__ a,
                                               float* __restrict__ h,
                                               float* __restrict__ s_src,
                                               float* __restrict__ s_tgt) {
    __shared__ float a_s[128];
    __shared__ float a_t[128];
    __shared__ float xrow[4][IN_F];
    int t = threadIdx.x;
    {
        int hh = t >> 5, j = t & 31;
        float v = a[t];
        if (j < 16) a_s[hh * 16 + j] = v;
        else        a_t[hh * 16 + (j - 16)] = v;
    }
    int wave = t >> 6, lane = t & 63;
    int n = blockIdx.x * 4 + wave;   // 12500*4 == 50000 exactly
    const float2* xg = (const float2*)(x + (size_t)n * IN_F);
    float2 pk = xg[lane];
    xrow[wave][2 * lane]     = pk.x;
    xrow[wave][2 * lane + 1] = pk.y;
    __syncthreads();

    int d = lane & 15, q = lane >> 4;
    int h0 = q, h1 = q + 4;
    int base0 = h0 * 2048 + d;     // W[h][f][d] = h*2048 + f*16 + d
    int base1 = h1 * 2048 + d;
    float acc0 = 0.f, acc1 = 0.f;
#pragma unroll 8
    for (int f = 0; f < IN_F; f++) {
        float xv = xrow[wave][f];
        acc0 = fmaf(xv, W[base0 + f * 16], acc0);
        acc1 = fmaf(xv, W[base1 + f * 16], acc1);
    }
    int c0 = lane;
    int c1 = lane + 64;
    h[(size_t)n * 128 + c0] = acc0;
    h[(size_t)n * 128 + c1] = acc1;

    float ps = acc0 * a_s[c0], pt = acc0 * a_t[c0];
    float qs = acc1 * a_s[c1], qt = acc1 * a_t[c1];
#pragma unroll
    for (int off = 1; off < 16; off <<= 1) {
        ps += __shfl_xor(ps, off, 64);
        pt += __shfl_xor(pt, off, 64);
        qs += __shfl_xor(qs, off, 64);
        qt += __shfl_xor(qt, off, 64);
    }
    if (d == 0) {
        s_src[n * 8 + h0] = ps;  s_tgt[n * 8 + h0] = pt;
        s_src[n * 8 + h1] = qs;  s_tgt[n * 8 + h1] = qt;
    }
}

// ---------------- maxred: per-head max over nodes of s_src and s_tgt
__global__ __launch_bounds__(256) void k_maxred(const float* __restrict__ s_src,
                                                const float* __restrict__ s_tgt,
                                                float* __restrict__ maxss,
                                                float* __restrict__ maxst) {
    __shared__ float red[2][4][8];
    int t = threadIdx.x;
    int i = blockIdx.x * 256 + t;   // 1563*256 >= 400000
    float vs = -INFINITY, vt = -INFINITY;
    if (i < N_NODES * 8) { vs = s_src[i]; vt = s_tgt[i]; }
    // i&7 == t&7 == head; reduce over lanes sharing t&7
#pragma unroll
    for (int off = 8; off < 64; off <<= 1) {
        vs = fmaxf(vs, __shfl_xor(vs, off, 64));
        vt = fmaxf(vt, __shfl_xor(vt, off, 64));
    }
    int lane = t & 63, wave = t >> 6;
    if (lane < 8) { red[0][wave][lane] = vs; red[1][wave][lane] = vt; }
    __syncthreads();
    if (t < 8) {
        float m = fmaxf(fmaxf(red[0][0][t], red[0][1][t]),
                        fmaxf(red[0][2][t], red[0][3][t]));
        atomicMaxF(&maxss[t], m);
    } else if (t < 16) {
        int j = t - 8;
        float m = fmaxf(fmaxf(red[1][0][j], red[1][1][j]),
                        fmaxf(red[1][2][j], red[1][3][j]));
        atomicMaxF(&maxst[j], m);
    }
}

// ---------------- hist: deg[tgt]++
__global__ __launch_bounds__(256) void k_hist(const int* __restrict__ tgtA,
                                              int* __restrict__ deg) {
    int e = blockIdx.x * 256 + threadIdx.x;
    atomicAdd(&deg[tgtA[e]], 1);
}

// ---------------- scan1: per-block (256-node chunk) sums
__global__ __launch_bounds__(256) void k_scan1(const int* __restrict__ deg,
                                               int* __restrict__ bsum) {
    __shared__ int wsum[4];
    int t = threadIdx.x;
    int idx = blockIdx.x * 256 + t;
    int v = (idx < N_NODES) ? deg[idx] : 0;
#pragma unroll
    for (int off = 1; off < 64; off <<= 1) v += __shfl_xor(v, off, 64);
    int lane = t & 63, w = t >> 6;
    if (lane == 0) wsum[w] = v;
    __syncthreads();
    if (t == 0) bsum[blockIdx.x] = wsum[0] + wsum[1] + wsum[2] + wsum[3];
}

// ---------------- scan2: exclusive scan of 196 block sums
__global__ __launch_bounds__(256) void k_scan2(const int* __restrict__ bsum,
                                               int* __restrict__ boff,
                                               int* __restrict__ rowptr) {
    __shared__ int wsum[4];
    __shared__ int woff[4];
    int t = threadIdx.x, lane = t & 63, w = t >> 6;
    int v = (t < 196) ? bsum[t] : 0;
    int inc = v;
#pragma unroll
    for (int off = 1; off < 64; off <<= 1) {
        int nn = __shfl_up(inc, off, 64);
        if (lane >= off) inc += nn;
    }
    if (lane == 63) wsum[w] = inc;
    __syncthreads();
    if (t == 0) {
        woff[0] = 0;
        woff[1] = wsum[0];
        woff[2] = wsum[0] + wsum[1];
        woff[3] = wsum[0] + wsum[1] + wsum[2];
    }
    __syncthreads();
    if (t < 196) boff[t] = woff[w] + inc - v;
    if (t == 0) rowptr[N_NODES] = N_EDGES;
}

// ---------------- scan3: local exclusive scan + block offset -> rowptr/cursor
__global__ __launch_bounds__(256) void k_scan3(const int* __restrict__ deg,
                                               const int* __restrict__ boff,
                                               int* __restrict__ rowptr,
                                               int* __restrict__ cursor) {
    __shared__ int wsum[4];
    __shared__ int woff[4];
    int t = threadIdx.x, lane = t & 63, w = t >> 6;
    int idx = blockIdx.x * 256 + t;
    int v = (idx < N_NODES) ? deg[idx] : 0;
    int inc = v;
#pragma unroll
    for (int off = 1; off < 64; off <<= 1) {
        int nn = __shfl_up(inc, off, 64);
        if (lane >= off) inc += nn;
    }
    if (lane == 63) wsum[w] = inc;
    __syncthreads();
    if (t == 0) {
        woff[0] = 0;
        woff[1] = wsum[0];
        woff[2] = wsum[0] + wsum[1];
        woff[3] = wsum[0] + wsum[1] + wsum[2];
    }
    __syncthreads();
    int excl = boff[blockIdx.x] + woff[w] + inc - v;
    if (idx < N_NODES) { rowptr[idx] = excl; cursor[idx] = excl; }
}

// ---------------- scatter: src_sorted by tgt (lean, 4-edge ILP)
__global__ __launch_bounds__(256) void k_scatter(const int* __restrict__ srcA,
                                                 const int* __restrict__ tgtA,
                                                 int* __restrict__ cursor,
                                                 int* __restrict__ src_sorted) {
    int base = blockIdx.x * 1024 + threadIdx.x;
    int e0 = base, e1 = base + 256, e2 = base + 512, e3 = base + 768;
    if (e3 < N_EDGES) {
        int s0 = srcA[e0], s1 = srcA[e1], s2 = srcA[e2], s3 = srcA[e3];
        int t0 = tgtA[e0], t1 = tgtA[e1], t2 = tgtA[e2], t3 = tgtA[e3];
        int p0 = atomicAdd(&cursor[t0], 1);
        int p1 = atomicAdd(&cursor[t1], 1);
        int p2 = atomicAdd(&cursor[t2], 1);
        int p3 = atomicAdd(&cursor[t3], 1);
        src_sorted[p0] = s0;
        src_sorted[p1] = s1;
        src_sorted[p2] = s2;
        src_sorted[p3] = s3;
    } else {
#pragma unroll
        for (int k = 0; k < 4; k++) {
            int e = base + k * 256;
            if (e < N_EDGES) {
                int s = srcA[e], tg = tgtA[e];
                int p = atomicAdd(&cursor[tg], 1);
                src_sorted[p] = s;
            }
        }
    }
}

// ---------------- fused: per-node atomic-free softmax + aggregation + bias
// one wave per node; lane owns cols 2*lane, 2*lane+1 (single head = lane>>3)
__global__ __launch_bounds__(256) void k_fused(const int* __restrict__ rowptr,
                                               const int* __restrict__ src_sorted,
                                               const float* __restrict__ s_src,
                                               const float* __restrict__ s_tgt,
                                               const float* __restrict__ maxss,
                                               const float* __restrict__ maxst,
                                               const float* __restrict__ h,
                                               const float* __restrict__ bias,
                                               float* __restrict__ outb) {
    int t = threadIdx.x;
    int wave = t >> 6, lane = t & 63;
    int n = blockIdx.x * 4 + wave;   // 12500*4 == 50000
    int head = lane >> 3;
    int c = 2 * lane;

    float mh = maxss[head] + maxst[head];
    float st = s_tgt[(size_t)n * 8 + head];
    int begin = rowptr[n], end = rowptr[n + 1];

    float accx = 0.f, accy = 0.f, den = 0.f;
    int e = begin;
    for (; e + 1 < end; e += 2) {
        int sA = src_sorted[e];
        int sB = src_sorted[e + 1];
        float ssA = s_src[(size_t)sA * 8 + head];
        float ssB = s_src[(size_t)sB * 8 + head];
        float2 hA = *(const float2*)(h + (size_t)sA * 128 + c);
        float2 hB = *(const float2*)(h + (size_t)sB * 128 + c);
        float vA = ssA + st; vA = vA >= 0.f ? vA : ALPHA * vA;
        float vB = ssB + st; vB = vB >= 0.f ? vB : ALPHA * vB;
        float exA = __expf(fminf(fmaxf(vA - mh, -20.f), 20.f));
        float exB = __expf(fminf(fmaxf(vB - mh, -20.f), 20.f));
        den += exA + exB;
        accx = fmaf(exA, hA.x, fmaf(exB, hB.x, accx));
        accy = fmaf(exA, hA.y, fmaf(exB, hB.y, accy));
    }
    if (e < end) {
        int sA = src_sorted[e];
        float ssA = s_src[(size_t)sA * 8 + head];
        float2 hA = *(const float2*)(h + (size_t)sA * 128 + c);
        float vA = ssA + st; vA = vA >= 0.f ? vA : ALPHA * vA;
        float exA = __expf(fminf(fmaxf(vA - mh, -20.f), 20.f));
        den += exA;
        accx = fmaf(exA, hA.x, accx);
        accy = fmaf(exA, hA.y, accy);
    }
    float r = 1.f / (den + EPSV);
    float2 o;
    o.x = accx * r + bias[c];
    o.y = accy * r + bias[c + 1];
    *(float2*)(outb + (size_t)n * 128 + c) = o;
}

extern "C" void kernel_launch(void* const* d_in, const int* in_sizes, int n_in,
                              void* d_out, int out_size, void* d_ws, size_t ws_size,
                              hipStream_t stream) {
    const float* x    = (const float*)d_in[0];
    const int*   ei   = (const int*)d_in[1];
    const float* W    = (const float*)d_in[2];
    const float* a    = (const float*)d_in[3];
    const float* bias = (const float*)d_in[4];
    float* outb = (float*)d_out;

    char* ws = (char*)d_ws;
    // layout (bytes):
    float* h          = (float*)(ws);                    // 25,600,000
    float* s_src      = (float*)(ws + 25600000);         //  1,600,000
    float* s_tgt      = (float*)(ws + 27200000);         //  1,600,000
    int*   deg        = (int*)  (ws + 28800000);         //    200,064
    int*   rowptr     = (int*)  (ws + 29000064);         //    200,064
    int*   cursor     = (int*)  (ws + 29200128);         //    200,064
    int*   src_sorted = (int*)  (ws + 29400192);         //  3,200,000
    int*   bsum       = (int*)  (ws + 32600192);         //      1,024
    int*   boff       = (int*)  (ws + 32601216);         //      1,024
    float* maxss      = (float*)(ws + 32602240);         //         32
    float* maxst      = (float*)(ws + 32602272);         //         32

    const int* srcA = ei;
    const int* tgtA = ei + N_EDGES;

    hipLaunchKernelGGL(k_init,    dim3(196),   dim3(256), 0, stream, deg, maxss, maxst);
    hipLaunchKernelGGL(k1_gemm,   dim3(12500), dim3(256), 0, stream, x, W, a, h, s_src, s_tgt);
    hipLaunchKernelGGL(k_hist,    dim3(3125),  dim3(256), 0, stream, tgtA, deg);
    hipLaunchKernelGGL(k_maxred,  dim3(1563),  dim3(256), 0, stream, s_src, s_tgt, maxss, maxst);
    hipLaunchKernelGGL(k_scan1,   dim3(196),   dim3(256), 0, stream, deg, bsum);
    hipLaunchKernelGGL(k_scan2,   dim3(1),     dim3(256), 0, stream, bsum, boff, rowptr);
    hipLaunchKernelGGL(k_scan3,   dim3(196),   dim3(256), 0, stream, deg, boff, rowptr, cursor);
    hipLaunchKernelGGL(k_scatter, dim3(782),   dim3(256), 0, stream, srcA, tgtA, cursor, src_sorted);
    hipLaunchKernelGGL(k_fused,   dim3(12500), dim3(256), 0, stream, rowptr, src_sorted, s_src, s_tgt, maxss, maxst, h, bias, outb);
}

// Round 5
// 347.167 us; speedup vs baseline: 1.3586x; 1.3586x over previous
//
#include <hip/hip_runtime.h>
#include <stdint.h>

#define N_NODES 50000
#define N_EDGES 800000
#define IN_F 128
#define HEADS 8
#define HEAD_DIM 16
#define ALPHA 0.2f
#define EPSV 1e-6f

// ---------------- init: zero deg
__global__ __launch_bounds__(256) void k_init(int* __restrict__ deg) {
    int i = blockIdx.x * 256 + threadIdx.x;
    if (i < N_NODES) deg[i] = 0;
}

// ---------------- k1: h = x @ W  (+ fused s_src/s_tgt projections)
// one wave per node; lane owns cols c0=lane, c1=lane+64 (col = head*16+d)
__global__ __launch_bounds__(256) void k1_gemm(const float* __restrict__ x,
                                               const float* __restrict__ W,
                                               const float* __restrict__ a,
                                               float* __restrict__ h,
                                               float* __restrict__ s_src,
                                               float* __restrict__ s_tgt) {
    __shared__ float a_s[128];
    __shared__ float a_t[128];
    __shared__ float xrow[4][IN_F];
    int t = threadIdx.x;
    {
        int hh = t >> 5, j = t & 31;
        float v = a[t];
        if (j < 16) a_s[hh * 16 + j] = v;
        else        a_t[hh * 16 + (j - 16)] = v;
    }
    int wave = t >> 6, lane = t & 63;
    int n = blockIdx.x * 4 + wave;   // 12500*4 == 50000 exactly
    const float2* xg = (const float2*)(x + (size_t)n * IN_F);
    float2 pk = xg[lane];
    xrow[wave][2 * lane]     = pk.x;
    xrow[wave][2 * lane + 1] = pk.y;
    __syncthreads();

    int d = lane & 15, q = lane >> 4;
    int h0 = q, h1 = q + 4;
    int base0 = h0 * 2048 + d;     // W[h][f][d] = h*2048 + f*16 + d
    int base1 = h1 * 2048 + d;
    float acc0 = 0.f, acc1 = 0.f;
#pragma unroll 8
    for (int f = 0; f < IN_F; f++) {
        float xv = xrow[wave][f];
        acc0 = fmaf(xv, W[base0 + f * 16], acc0);
        acc1 = fmaf(xv, W[base1 + f * 16], acc1);
    }
    int c0 = lane;
    int c1 = lane + 64;
    h[(size_t)n * 128 + c0] = acc0;
    h[(size_t)n * 128 + c1] = acc1;

    float ps = acc0 * a_s[c0], pt = acc0 * a_t[c0];
    float qs = acc1 * a_s[c1], qt = acc1 * a_t[c1];
#pragma unroll
    for (int off = 1; off < 16; off <<= 1) {
        ps += __shfl_xor(ps, off, 64);
        pt += __shfl_xor(pt, off, 64);
        qs += __shfl_xor(qs, off, 64);
        qt += __shfl_xor(qt, off, 64);
    }
    if (d == 0) {
        s_src[n * 8 + h0] = ps;  s_tgt[n * 8 + h0] = pt;
        s_src[n * 8 + h1] = qs;  s_tgt[n * 8 + h1] = qt;
    }
}

// ---------------- maxred stage 1: per-block partial per-head maxes (no atomics)
__global__ __launch_bounds__(256) void k_maxred1(const float* __restrict__ s_src,
                                                 const float* __restrict__ s_tgt,
                                                 float* __restrict__ part_ss,
                                                 float* __restrict__ part_st) {
    __shared__ float red[2][4][8];
    int t = threadIdx.x;
    int i = blockIdx.x * 256 + t;   // 1563*256 >= 400000
    float vs = -INFINITY, vt = -INFINITY;
    if (i < N_NODES * 8) { vs = s_src[i]; vt = s_tgt[i]; }
    // t&7 == head within this slice; reduce lanes sharing t&7
#pragma unroll
    for (int off = 8; off < 64; off <<= 1) {
        vs = fmaxf(vs, __shfl_xor(vs, off, 64));
        vt = fmaxf(vt, __shfl_xor(vt, off, 64));
    }
    int lane = t & 63, wave = t >> 6;
    if (lane < 8) { red[0][wave][lane] = vs; red[1][wave][lane] = vt; }
    __syncthreads();
    if (t < 8) {
        float m = fmaxf(fmaxf(red[0][0][t], red[0][1][t]),
                        fmaxf(red[0][2][t], red[0][3][t]));
        part_ss[blockIdx.x * 8 + t] = m;
    } else if (t < 16) {
        int j = t - 8;
        float m = fmaxf(fmaxf(red[1][0][j], red[1][1][j]),
                        fmaxf(red[1][2][j], red[1][3][j]));
        part_st[blockIdx.x * 8 + j] = m;
    }
}

// ---------------- maxred stage 2: one block reduces 1563*8 partials
__global__ __launch_bounds__(256) void k_maxred2(const float* __restrict__ part_ss,
                                                 const float* __restrict__ part_st,
                                                 float* __restrict__ maxss,
                                                 float* __restrict__ maxst) {
    __shared__ float red[2][4][8];
    int t = threadIdx.x;
    const int TOT = 1563 * 8;
    float vs = -INFINITY, vt = -INFINITY;
    for (int j = t; j < TOT; j += 256) {   // stride 256 % 8 == 0 keeps head = t&7
        vs = fmaxf(vs, part_ss[j]);
        vt = fmaxf(vt, part_st[j]);
    }
#pragma unroll
    for (int off = 8; off < 64; off <<= 1) {
        vs = fmaxf(vs, __shfl_xor(vs, off, 64));
        vt = fmaxf(vt, __shfl_xor(vt, off, 64));
    }
    int lane = t & 63, wave = t >> 6;
    if (lane < 8) { red[0][wave][lane] = vs; red[1][wave][lane] = vt; }
    __syncthreads();
    if (t < 8) {
        maxss[t] = fmaxf(fmaxf(red[0][0][t], red[0][1][t]),
                         fmaxf(red[0][2][t], red[0][3][t]));
    } else if (t < 16) {
        int j = t - 8;
        maxst[j] = fmaxf(fmaxf(red[1][0][j], red[1][1][j]),
                         fmaxf(red[1][2][j], red[1][3][j]));
    }
}

// ---------------- hist: deg[tgt]++
__global__ __launch_bounds__(256) void k_hist(const int* __restrict__ tgtA,
                                              int* __restrict__ deg) {
    int e = blockIdx.x * 256 + threadIdx.x;
    atomicAdd(&deg[tgtA[e]], 1);
}

// ---------------- scan1: per-block (256-node chunk) sums
__global__ __launch_bounds__(256) void k_scan1(const int* __restrict__ deg,
                                               int* __restrict__ bsum) {
    __shared__ int wsum[4];
    int t = threadIdx.x;
    int idx = blockIdx.x * 256 + t;
    int v = (idx < N_NODES) ? deg[idx] : 0;
#pragma unroll
    for (int off = 1; off < 64; off <<= 1) v += __shfl_xor(v, off, 64);
    int lane = t & 63, w = t >> 6;
    if (lane == 0) wsum[w] = v;
    __syncthreads();
    if (t == 0) bsum[blockIdx.x] = wsum[0] + wsum[1] + wsum[2] + wsum[3];
}

// ---------------- scan2: exclusive scan of 196 block sums
__global__ __launch_bounds__(256) void k_scan2(const int* __restrict__ bsum,
                                               int* __restrict__ boff,
                                               int* __restrict__ rowptr) {
    __shared__ int wsum[4];
    __shared__ int woff[4];
    int t = threadIdx.x, lane = t & 63, w = t >> 6;
    int v = (t < 196) ? bsum[t] : 0;
    int inc = v;
#pragma unroll
    for (int off = 1; off < 64; off <<= 1) {
        int nn = __shfl_up(inc, off, 64);
        if (lane >= off) inc += nn;
    }
    if (lane == 63) wsum[w] = inc;
    __syncthreads();
    if (t == 0) {
        woff[0] = 0;
        woff[1] = wsum[0];
        woff[2] = wsum[0] + wsum[1];
        woff[3] = wsum[0] + wsum[1] + wsum[2];
    }
    __syncthreads();
    if (t < 196) boff[t] = woff[w] + inc - v;
    if (t == 0) rowptr[N_NODES] = N_EDGES;
}

// ---------------- scan3: local exclusive scan + block offset -> rowptr/cursor
__global__ __launch_bounds__(256) void k_scan3(const int* __restrict__ deg,
                                               const int* __restrict__ boff,
                                               int* __restrict__ rowptr,
                                               int* __restrict__ cursor) {
    __shared__ int wsum[4];
    __shared__ int woff[4];
    int t = threadIdx.x, lane = t & 63, w = t >> 6;
    int idx = blockIdx.x * 256 + t;
    int v = (idx < N_NODES) ? deg[idx] : 0;
    int inc = v;
#pragma unroll
    for (int off = 1; off < 64; off <<= 1) {
        int nn = __shfl_up(inc, off, 64);
        if (lane >= off) inc += nn;
    }
    if (lane == 63) wsum[w] = inc;
    __syncthreads();
    if (t == 0) {
        woff[0] = 0;
        woff[1] = wsum[0];
        woff[2] = wsum[0] + wsum[1];
        woff[3] = wsum[0] + wsum[1] + wsum[2];
    }
    __syncthreads();
    int excl = boff[blockIdx.x] + woff[w] + inc - v;
    if (idx < N_NODES) { rowptr[idx] = excl; cursor[idx] = excl; }
}

// ---------------- scatter: src_sorted by tgt (lean, 4-edge ILP)
__global__ __launch_bounds__(256) void k_scatter(const int* __restrict__ srcA,
                                                 const int* __restrict__ tgtA,
                                                 int* __restrict__ cursor,
                                                 int* __restrict__ src_sorted) {
    int base = blockIdx.x * 1024 + threadIdx.x;
    int e0 = base, e1 = base + 256, e2 = base + 512, e3 = base + 768;
    if (e3 < N_EDGES) {
        int s0 = srcA[e0], s1 = srcA[e1], s2 = srcA[e2], s3 = srcA[e3];
        int t0 = tgtA[e0], t1 = tgtA[e1], t2 = tgtA[e2], t3 = tgtA[e3];
        int p0 = atomicAdd(&cursor[t0], 1);
        int p1 = atomicAdd(&cursor[t1], 1);
        int p2 = atomicAdd(&cursor[t2], 1);
        int p3 = atomicAdd(&cursor[t3], 1);
        src_sorted[p0] = s0;
        src_sorted[p1] = s1;
        src_sorted[p2] = s2;
        src_sorted[p3] = s3;
    } else {
#pragma unroll
        for (int k = 0; k < 4; k++) {
            int e = base + k * 256;
            if (e < N_EDGES) {
                int s = srcA[e], tg = tgtA[e];
                int p = atomicAdd(&cursor[tg], 1);
                src_sorted[p] = s;
            }
        }
    }
}

// ---------------- fused: per-node atomic-free softmax + aggregation + bias
// one wave per node; lane owns cols 2*lane, 2*lane+1 (single head = lane>>3)
__global__ __launch_bounds__(256) void k_fused(const int* __restrict__ rowptr,
                                               const int* __restrict__ src_sorted,
                                               const float* __restrict__ s_src,
                                               const float* __restrict__ s_tgt,
                                               const float* __restrict__ maxss,
                                               const float* __restrict__ maxst,
                                               const float* __restrict__ h,
                                               const float* __restrict__ bias,
                                               float* __restrict__ outb) {
    int t = threadIdx.x;
    int wave = t >> 6, lane = t & 63;
    int n = blockIdx.x * 4 + wave;   // 12500*4 == 50000
    int head = lane >> 3;
    int c = 2 * lane;

    float mh = maxss[head] + maxst[head];
    float st = s_tgt[(size_t)n * 8 + head];
    int begin = rowptr[n], end = rowptr[n + 1];

    float accx = 0.f, accy = 0.f, den = 0.f;
    int e = begin;
    for (; e + 1 < end; e += 2) {
        int sA = src_sorted[e];
        int sB = src_sorted[e + 1];
        float ssA = s_src[(size_t)sA * 8 + head];
        float ssB = s_src[(size_t)sB * 8 + head];
        float2 hA = *(const float2*)(h + (size_t)sA * 128 + c);
        float2 hB = *(const float2*)(h + (size_t)sB * 128 + c);
        float vA = ssA + st; vA = vA >= 0.f ? vA : ALPHA * vA;
        float vB = ssB + st; vB = vB >= 0.f ? vB : ALPHA * vB;
        float exA = __expf(fminf(fmaxf(vA - mh, -20.f), 20.f));
        float exB = __expf(fminf(fmaxf(vB - mh, -20.f), 20.f));
        den += exA + exB;
        accx = fmaf(exA, hA.x, fmaf(exB, hB.x, accx));
        accy = fmaf(exA, hA.y, fmaf(exB, hB.y, accy));
    }
    if (e < end) {
        int sA = src_sorted[e];
        float ssA = s_src[(size_t)sA * 8 + head];
        float2 hA = *(const float2*)(h + (size_t)sA * 128 + c);
        float vA = ssA + st; vA = vA >= 0.f ? vA : ALPHA * vA;
        float exA = __expf(fminf(fmaxf(vA - mh, -20.f), 20.f));
        den += exA;
        accx = fmaf(exA, hA.x, accx);
        accy = fmaf(exA, hA.y, accy);
    }
    float r = 1.f / (den + EPSV);
    float2 o;
    o.x = accx * r + bias[c];
    o.y = accy * r + bias[c + 1];
    *(float2*)(outb + (size_t)n * 128 + c) = o;
}

extern "C" void kernel_launch(void* const* d_in, const int* in_sizes, int n_in,
                              void* d_out, int out_size, void* d_ws, size_t ws_size,
                              hipStream_t stream) {
    const float* x    = (const float*)d_in[0];
    const int*   ei   = (const int*)d_in[1];
    const float* W    = (const float*)d_in[2];
    const float* a    = (const float*)d_in[3];
    const float* bias = (const float*)d_in[4];
    float* outb = (float*)d_out;

    char* ws = (char*)d_ws;
    // layout (bytes):
    float* h          = (float*)(ws);                    // 25,600,000
    float* s_src      = (float*)(ws + 25600000);         //  1,600,000
    float* s_tgt      = (float*)(ws + 27200000);         //  1,600,000
    int*   deg        = (int*)  (ws + 28800000);         //    200,064
    int*   rowptr     = (int*)  (ws + 29000064);         //    200,064
    int*   cursor     = (int*)  (ws + 29200128);         //    200,064
    int*   src_sorted = (int*)  (ws + 29400192);         //  3,200,000
    int*   bsum       = (int*)  (ws + 32600192);         //      1,024
    int*   boff       = (int*)  (ws + 32601216);         //      1,024
    float* part_ss    = (float*)(ws + 32602240);         //     50,176
    float* part_st    = (float*)(ws + 32652416);         //     50,176
    float* maxss      = (float*)(ws + 32702592);         //         32
    float* maxst      = (float*)(ws + 32702624);         //         32

    const int* srcA = ei;
    const int* tgtA = ei + N_EDGES;

    hipLaunchKernelGGL(k_init,    dim3(196),   dim3(256), 0, stream, deg);
    hipLaunchKernelGGL(k1_gemm,   dim3(12500), dim3(256), 0, stream, x, W, a, h, s_src, s_tgt);
    hipLaunchKernelGGL(k_hist,    dim3(3125),  dim3(256), 0, stream, tgtA, deg);
    hipLaunchKernelGGL(k_maxred1, dim3(1563),  dim3(256), 0, stream, s_src, s_tgt, part_ss, part_st);
    hipLaunchKernelGGL(k_maxred2, dim3(1),     dim3(256), 0, stream, part_ss, part_st, maxss, maxst);
    hipLaunchKernelGGL(k_scan1,   dim3(196),   dim3(256), 0, stream, deg, bsum);
    hipLaunchKernelGGL(k_scan2,   dim3(1),     dim3(256), 0, stream, bsum, boff, rowptr);
    hipLaunchKernelGGL(k_scan3,   dim3(196),   dim3(256), 0, stream, deg, boff, rowptr, cursor);
    hipLaunchKernelGGL(k_scatter, dim3(782),   dim3(256), 0, stream, srcA, tgtA, cursor, src_sorted);
    hipLaunchKernelGGL(k_fused,   dim3(12500), dim3(256), 0, stream, rowptr, src_sorted, s_src, s_tgt, maxss, maxst, h, bias, outb);
}